// Round 13
// baseline (160.723 us; speedup 1.0000x reference)
//
#include <hip/hip_runtime.h>
#include <cmath>

// ---------------------------------------------------------------------------
// NeuralField: hashgrid encode (8 levels x 8 feats, smoothstep) + MLP
// 64 -> 256 -> 256 -> 256 -> 1 (ReLU x3, linear out), N = 262144 points.
// R13: deep wf prefetch. R12 (104 us): MfmaUtil 34%, occupancy 60%, ~60% of
// cycles in waitcnt. Binding stall = wf global load (L2 ~200 cyc) at
// prefetch depth 1. Fix per AITER/hipBLASLt pattern: ring of 4 wf loads in
// flight (preamble kb 0-2, in-loop kb+3; kb=0 still preloaded before the
// inter-layer barrier). af stays depth-1 (LDS). Regs: 40V + 32acc + 8 extra
// wf ~ 80 <= 85 cap of (512,6) -> no spill, 3 blocks/CU kept.
// Everything else = R12 (32x32x16, fused final layer, in-place act buffer).
// Spill tripwire: FETCH/WRITE >> 5 MB.
// ---------------------------------------------------------------------------

#define N_LEVELS 8
#define TABLE_PAD 8192
#define TILE_M 64
#define ACT_STRIDE 264       // shorts per activation row
#define ENC_STRIDE 72        // shorts per encode row

typedef __attribute__((ext_vector_type(8))) short short8;
typedef __attribute__((ext_vector_type(16))) float float16v;

struct LevelParams {
  float scale[N_LEVELS];
  int   res[N_LEVELS];
  int   size[N_LEVELS];
};

__device__ __forceinline__ unsigned short f2bf(float f) {
  unsigned int u = __float_as_uint(f);
  u += 0x7fffu + ((u >> 16) & 1u);      // round to nearest even
  return (unsigned short)(u >> 16);
}
__device__ __forceinline__ unsigned int pack2bf(float a, float b) {
  a = a > 0.f ? a : 0.f;
  b = b > 0.f ? b : 0.f;
  return (unsigned int)f2bf(a) | ((unsigned int)f2bf(b) << 16);
}

// Pack W (K x 256 row-major f32) -> bf16 [k/16][n][k%16]: one lane's 16 B
// A-frag for 32x32x16 (feature n, k-half h8) is contiguous at n*16 + h8*8.
// Wp layout: [W0p: 4*4096][W1p: 16*4096][W2p: 16*4096] shorts.
__global__ void pack_weights_kernel(const float* __restrict__ W0,
                                    const float* __restrict__ W1,
                                    const float* __restrict__ W2,
                                    unsigned short* __restrict__ Wp) {
  int tid = blockIdx.x * blockDim.x + threadIdx.x;
  const float* src;
  int base, e;
  if (tid < 16384)        { src = W0; base = 0;     e = tid;         }
  else if (tid < 81920)   { src = W1; base = 16384; e = tid - 16384; }
  else if (tid < 147456)  { src = W2; base = 81920; e = tid - 81920; }
  else return;
  int ki = e & 15;
  int n  = (e >> 4) & 255;
  int kb = e >> 12;
  unsigned int u = __float_as_uint(src[(kb * 16 + ki) * 256 + n]);
  u += 0x7fffu + ((u >> 16) & 1u);
  Wp[base + e] = (unsigned short)(u >> 16);
}

__global__ __launch_bounds__(512, 6) void neural_field_kernel(
    const float* __restrict__ x,
    const float* __restrict__ table,
    const unsigned short* __restrict__ Wp,
    const float* __restrict__ W3,
    float* __restrict__ out,
    LevelParams P) {
  // Padded layouts, data stored [point m][feature k]:
  //   enc: (m, k) -> m*72 + k      act: (m, k) -> m*264 + k
  __shared__ unsigned short bufE[TILE_M * ENC_STRIDE];   //  9 KB (-> fsum)
  __shared__ unsigned short bufA[TILE_M * ACT_STRIDE];   // 33 KB, in-place

  const int t  = threadIdx.x;
  const int g0 = blockIdx.x * TILE_M;

  const int lane  = t & 63;
  const int w     = t >> 6;       // 0..7
  const int l31   = lane & 31;
  const int h8    = lane >> 5;    // 0/1: k-half within a 16-k step
  const int wbase = w * 32;       // this wave's 32 OUTPUT FEATURES

  // Per-wave weight A-frag base offset (elements) in a layer's packed W.
  const int woff = (wbase + l31) * 16 + h8 * 8;

  // ------------- Phase 1: hashgrid encode, 1 level/thread -> bufE ----------
  {
    int p = t & 63;        // point within tile
    int l = t >> 6;        // level 0..7
    float2 xy = ((const float2*)x)[g0 + p];
    float scale = P.scale[l];
    int res = P.res[l], size = P.size[l];
    float posx = xy.x * scale + 0.5f;
    float posy = xy.y * scale + 0.5f;
    float pgx = floorf(posx), pgy = floorf(posy);
    float fx = posx - pgx, fy = posy - pgy;
    float wx = fx * fx * (3.0f - 2.0f * fx);
    float wy = fy * fy * (3.0f - 2.0f * fy);
    int px = (int)pgx, py = (int)pgy;
    float acc[8] = {0, 0, 0, 0, 0, 0, 0, 0};
    for (int dy = 0; dy < 2; ++dy) {
      float wyv = dy ? wy : 1.0f - wy;
      for (int dx = 0; dx < 2; ++dx) {
        float wgt = (dx ? wx : 1.0f - wx) * wyv;
        int idx = (px + dx) + (py + dy) * res;
        if (idx >= size) idx -= size;   // idx < 2*size always
        const float4* tp =
            (const float4*)(table + ((size_t)l * TABLE_PAD + idx) * 8);
        float4 t0 = tp[0], t1 = tp[1];
        acc[0] += wgt * t0.x; acc[1] += wgt * t0.y;
        acc[2] += wgt * t0.z; acc[3] += wgt * t0.w;
        acc[4] += wgt * t1.x; acc[5] += wgt * t1.y;
        acc[6] += wgt * t1.z; acc[7] += wgt * t1.w;
      }
    }
    union { unsigned short s[8]; short8 v; } u;
    for (int j = 0; j < 8; ++j) u.s[j] = f2bf(acc[j]);
    *(short8*)&bufE[p * ENC_STRIDE + l * 8] = u.v;
  }

  // ---- MFMA layer (transposed, 32x32x16): D = W^T[32 x K] @ X^T[K x 64] ---
  // A-frag (weights): row n = wbase+l31, k = s*16 + h8*8 + j.
  // B-frag (acts):    col m = pt*32+l31, k = s*16 + h8*8 + j.
  // D: col m = pt*32+l31; rows: reg 4q+r -> n = wbase + 8q + 4h8 + r.
  // wf pipeline: ring of 4 fragments in flight (kb..kb+3).
  auto run_layer = [&](const unsigned short* inb, int in_stride,
                       unsigned short* outb, const unsigned short* Wpl,
                       int KB, short8 wf0, bool inplace, bool fuse_final,
                       float* fsum) {
    float16v acc[2];
    for (int j = 0; j < 16; ++j) { acc[0][j] = 0.f; acc[1][j] = 0.f; }

    const unsigned short* ap0 = &inb[l31 * in_stride + h8 * 8];
    const unsigned short* ap1 = ap0 + 32 * in_stride;
    const unsigned short* wp  = Wpl + woff;

    float w3f[16];
    if (fuse_final) {
      for (int q = 0; q < 4; ++q) {
        float4 wv = *(const float4*)(W3 + wbase + 8 * q + 4 * h8);
        w3f[4 * q + 0] = wv.x; w3f[4 * q + 1] = wv.y;
        w3f[4 * q + 2] = wv.z; w3f[4 * q + 3] = wv.w;
      }
    }

    // wf ring: wfr[i & 3] holds fragment for k-block i while in flight.
    short8 wfr[4];
    wfr[0] = wf0;                                   // preloaded pre-barrier
    wfr[1] = *(const short8*)(wp + ((1 < KB) ? 1 : KB - 1) * 4096);
    wfr[2] = *(const short8*)(wp + ((2 < KB) ? 2 : KB - 1) * 4096);

    short8 af0[2];
    af0[0] = *(const short8*)(ap0);
    af0[1] = *(const short8*)(ap1);

#pragma unroll
    for (int kb = 0; kb < KB; ++kb) {
      int kn = (kb + 1 < KB) ? kb + 1 : kb;         // af prefetch index
      int kf = (kb + 3 < KB) ? kb + 3 : KB - 1;     // wf prefetch index
      wfr[(kb + 3) & 3] = *(const short8*)(wp + kf * 4096);
      short8 af1[2];
      af1[0] = *(const short8*)(ap0 + kn * 16);
      af1[1] = *(const short8*)(ap1 + kn * 16);

      acc[0] = __builtin_amdgcn_mfma_f32_32x32x16_bf16(wfr[kb & 3], af0[0],
                                                       acc[0], 0, 0, 0);
      acc[1] = __builtin_amdgcn_mfma_f32_32x32x16_bf16(wfr[kb & 3], af0[1],
                                                       acc[1], 0, 0, 0);
      af0[0] = af1[0]; af0[1] = af1[1];
    }

    if (inplace) __syncthreads();   // all K-loop reads done before overwrite

    if (!fuse_final) {
      // Epilogue: ReLU + bf16 pack; 4 b64 writes per pt-tile, already in
      // the next layer's [m][k-contiguous] layout.
      for (int pt = 0; pt < 2; ++pt) {
        int m = pt * 32 + l31;
        for (int q = 0; q < 4; ++q) {
          int n0 = wbase + 8 * q + 4 * h8;
          uint2 pk;
          pk.x = pack2bf(acc[pt][4 * q + 0], acc[pt][4 * q + 1]);
          pk.y = pack2bf(acc[pt][4 * q + 2], acc[pt][4 * q + 3]);
          *(uint2*)&outb[m * ACT_STRIDE + n0] = pk;
        }
      }
    } else {
      // Fused final layer: per-lane relu-dot over this wave's 32 features
      // (16 per k-half), combine halves via shfl_xor(32), stage per-wave
      // partials to fsum[m*9 + w] (stride 9 breaks write conflicts).
      float part0 = 0.f, part1 = 0.f;
      for (int j = 0; j < 16; ++j) {
        float v0 = acc[0][j]; v0 = v0 > 0.f ? v0 : 0.f;
        float v1 = acc[1][j]; v1 = v1 > 0.f ? v1 : 0.f;
        part0 += v0 * w3f[j];
        part1 += v1 * w3f[j];
      }
      part0 += __shfl_xor(part0, 32);
      part1 += __shfl_xor(part1, 32);
      float val = h8 ? part1 : part0;   // lane holds m = h8*32 + l31 = lane
      fsum[lane * 9 + w] = val;
    }
  };

  float* fsum = (float*)bufE;           // bufE dead after layer 0

  short8 wf = *(const short8*)(Wp + woff);          // L0 wf preload
  __syncthreads();
  // Layer 0: bufE -> bufA (disjoint buffers, no in-place hazard)
  run_layer(bufE, ENC_STRIDE, bufA, Wp, 4, wf, false, false, fsum);
  wf = *(const short8*)(Wp + 16384 + woff);         // L1 wf preload
  __syncthreads();
  // Layer 1: bufA -> bufA IN-PLACE (mid-layer barrier inside)
  run_layer(bufA, ACT_STRIDE, bufA, Wp + 16384, 16, wf, true, false, fsum);
  wf = *(const short8*)(Wp + 81920 + woff);         // L2 wf preload
  __syncthreads();
  // Layer 2 + final: reads bufA, writes only fsum (bufE region, disjoint)
  run_layer(bufA, ACT_STRIDE, nullptr, Wp + 81920, 16, wf, false, true, fsum);
  __syncthreads();

  // ---------------- Cross-wave reduce of fsum -> out -----------------------
  {
    int p = t >> 3;          // point within tile (0..63)
    int q = t & 7;           // wave index being summed
    float v = fsum[p * 9 + q];
    v += __shfl_xor(v, 1);
    v += __shfl_xor(v, 2);
    v += __shfl_xor(v, 4);
    if (q == 0) out[g0 + p] = v;
  }
}

extern "C" void kernel_launch(void* const* d_in, const int* in_sizes, int n_in,
                              void* d_out, int out_size, void* d_ws,
                              size_t ws_size, hipStream_t stream) {
  const float* x     = (const float*)d_in[0];
  const float* table = (const float*)d_in[1];
  const float* W0    = (const float*)d_in[2];
  const float* W1    = (const float*)d_in[3];
  const float* W2    = (const float*)d_in[4];
  const float* W3    = (const float*)d_in[5];
  float* out = (float*)d_out;
  int N = in_sizes[0] / 2;

  unsigned short* Wp = (unsigned short*)d_ws;   // 147456 bf16 = 288 KB

  // Level params, double precision to match the Python reference exactly.
  LevelParams P;
  const double c = 1.2599210739135742;
  double m = 1.0;
  for (int l = 0; l < N_LEVELS; ++l) {
    double scale_d = 16.0 * m - 1.0;
    int res = (int)std::ceil(scale_d) + 1;
    long long sz = ((long long)res * res + 7) / 8 * 8;
    if (sz > (1LL << 19)) sz = 1LL << 19;
    P.scale[l] = (float)scale_d;
    P.res[l]   = res;
    P.size[l]  = (int)sz;
    m *= c;
  }

  hipLaunchKernelGGL(pack_weights_kernel, dim3(576), dim3(256), 0, stream,
                     W0, W1, W2, Wp);
  hipLaunchKernelGGL(neural_field_kernel, dim3(N / TILE_M), dim3(512), 0,
                     stream, x, table, Wp, W3, out, P);
}

// Round 15
// 156.909 us; speedup vs baseline: 1.0243x; 1.0243x over previous
//
#include <hip/hip_runtime.h>
#include <cmath>

// ---------------------------------------------------------------------------
// NeuralField: hashgrid encode (8 levels x 8 feats, smoothstep) + MLP
// 64 -> 256 -> 256 -> 256 -> 1 (ReLU x3, linear out), N = 262144 points.
// R15: TILE_M=96 on the PROVEN R12/R13 dataflow. R14 (TILE_M=128 + encode
// fused into the act buffer) produced nondeterministic 1e-3-level errors --
// reverted to: separate bufE encode staging, layer 1 in-place with internal
// barrier, layer 2 + final dot fused writing fsum (aliased on dead bufE).
// Each wave: 32 feats x 96 pts (3 pt-tiles, acc 48 regs) -> weight L2
// traffic per point cut 33% (288 KB per 96 pts; was per 64). LDS 63 KB ->
// 2 blocks/CU at (512,4). N not divisible by 96 -> grid 2731, clamp guards
// on x load + out store (tail columns independent, clamped data, no NaN).
// Spill tripwire: FETCH/WRITE >> 5 MB.
// ---------------------------------------------------------------------------

#define N_LEVELS 8
#define TABLE_PAD 8192
#define TILE_M 96
#define ACT_STRIDE 264       // shorts per activation row (16B-aligned rows)
#define ENC_STRIDE 72        // shorts per encode row     (16B-aligned rows)

typedef __attribute__((ext_vector_type(8))) short short8;
typedef __attribute__((ext_vector_type(16))) float float16v;

struct LevelParams {
  float scale[N_LEVELS];
  int   res[N_LEVELS];
  int   size[N_LEVELS];
};

__device__ __forceinline__ unsigned short f2bf(float f) {
  unsigned int u = __float_as_uint(f);
  u += 0x7fffu + ((u >> 16) & 1u);      // round to nearest even
  return (unsigned short)(u >> 16);
}
__device__ __forceinline__ unsigned int pack2bf(float a, float b) {
  a = a > 0.f ? a : 0.f;
  b = b > 0.f ? b : 0.f;
  return (unsigned int)f2bf(a) | ((unsigned int)f2bf(b) << 16);
}

// Pack W (K x 256 row-major f32) -> bf16 [k/16][n][k%16]: one lane's 16 B
// A-frag for 32x32x16 (feature n, k-half h8) is contiguous at n*16 + h8*8.
// Wp layout: [W0p: 4*4096][W1p: 16*4096][W2p: 16*4096] shorts.
__global__ void pack_weights_kernel(const float* __restrict__ W0,
                                    const float* __restrict__ W1,
                                    const float* __restrict__ W2,
                                    unsigned short* __restrict__ Wp) {
  int tid = blockIdx.x * blockDim.x + threadIdx.x;
  const float* src;
  int base, e;
  if (tid < 16384)        { src = W0; base = 0;     e = tid;         }
  else if (tid < 81920)   { src = W1; base = 16384; e = tid - 16384; }
  else if (tid < 147456)  { src = W2; base = 81920; e = tid - 81920; }
  else return;
  int ki = e & 15;
  int n  = (e >> 4) & 255;
  int kb = e >> 12;
  unsigned int u = __float_as_uint(src[(kb * 16 + ki) * 256 + n]);
  u += 0x7fffu + ((u >> 16) & 1u);
  Wp[base + e] = (unsigned short)(u >> 16);
}

__global__ __launch_bounds__(512, 4) void neural_field_kernel(
    const float* __restrict__ x,
    const float* __restrict__ table,
    const unsigned short* __restrict__ Wp,
    const float* __restrict__ W3,
    float* __restrict__ out,
    LevelParams P, int Ntot) {
  // Padded layouts, data stored [point m][feature k]:
  //   enc: (m, k) -> m*72 + k      act: (m, k) -> m*264 + k
  __shared__ unsigned short bufE[TILE_M * ENC_STRIDE];   // 13.8 KB (-> fsum)
  __shared__ unsigned short bufA[TILE_M * ACT_STRIDE];   // 50.7 KB, in-place

  const int t  = threadIdx.x;
  const int g0 = blockIdx.x * TILE_M;

  const int lane  = t & 63;
  const int w     = t >> 6;       // 0..7
  const int l31   = lane & 31;
  const int h8    = lane >> 5;    // 0/1: k-half within a 16-k step
  const int wbase = w * 32;       // this wave's 32 OUTPUT FEATURES

  // Per-wave weight A-frag base offset (elements) in a layer's packed W.
  const int woff = (wbase + l31) * 16 + h8 * 8;

  // ------------- Phase 1: hashgrid encode, 2 levels/thread -> bufE ---------
  {
    int p  = t & 127;      // candidate point within tile
    int lg = t >> 7;       // 0..3 -> levels 2lg, 2lg+1
    if (p < TILE_M) {
      int gi = g0 + p;
      if (gi >= Ntot) gi = Ntot - 1;          // tail clamp (output discarded)
      float2 xy = ((const float2*)x)[gi];
      for (int li = 0; li < 2; ++li) {
        int l = lg * 2 + li;
        float scale = P.scale[l];
        int res = P.res[l], size = P.size[l];
        float posx = xy.x * scale + 0.5f;
        float posy = xy.y * scale + 0.5f;
        float pgx = floorf(posx), pgy = floorf(posy);
        float fx = posx - pgx, fy = posy - pgy;
        float wx = fx * fx * (3.0f - 2.0f * fx);
        float wy = fy * fy * (3.0f - 2.0f * fy);
        int px = (int)pgx, py = (int)pgy;
        float acc[8] = {0, 0, 0, 0, 0, 0, 0, 0};
        for (int dy = 0; dy < 2; ++dy) {
          float wyv = dy ? wy : 1.0f - wy;
          for (int dx = 0; dx < 2; ++dx) {
            float wgt = (dx ? wx : 1.0f - wx) * wyv;
            int idx = (px + dx) + (py + dy) * res;
            if (idx >= size) idx -= size;   // idx < 2*size always
            const float4* tp =
                (const float4*)(table + ((size_t)l * TABLE_PAD + idx) * 8);
            float4 t0 = tp[0], t1 = tp[1];
            acc[0] += wgt * t0.x; acc[1] += wgt * t0.y;
            acc[2] += wgt * t0.z; acc[3] += wgt * t0.w;
            acc[4] += wgt * t1.x; acc[5] += wgt * t1.y;
            acc[6] += wgt * t1.z; acc[7] += wgt * t1.w;
          }
        }
        union { unsigned short s[8]; short8 v; } u;
        for (int j = 0; j < 8; ++j) u.s[j] = f2bf(acc[j]);
        *(short8*)&bufE[p * ENC_STRIDE + l * 8] = u.v;
      }
    }
  }

  // ---- MFMA layer (transposed, 32x32x16): D = W^T[32 x K] @ X^T[K x 96] ---
  // A-frag (weights): row n = wbase+l31, k = kb*16 + h8*8 + j.
  // B-frag (acts):    col m = pt*32+l31, k = kb*16 + h8*8 + j, pt = 0..2.
  // D: col m = pt*32+l31; rows: reg 4q+r -> n = wbase + 8q + 4h8 + r.
  auto run_layer = [&](const unsigned short* inb, int in_stride,
                       unsigned short* outb, const unsigned short* Wpl,
                       int KB, short8 wf0, bool inplace, bool fuse_final,
                       float* fsum) {
    float16v acc[3];
    for (int pt = 0; pt < 3; ++pt)
      for (int j = 0; j < 16; ++j) acc[pt][j] = 0.f;

    const unsigned short* ap[3];
    for (int pt = 0; pt < 3; ++pt)
      ap[pt] = &inb[(pt * 32 + l31) * in_stride + h8 * 8];
    const unsigned short* wp = Wpl + woff;

    short8 af0[3];
    for (int pt = 0; pt < 3; ++pt)
      af0[pt] = *(const short8*)(ap[pt]);

#pragma unroll
    for (int kb = 0; kb < KB; ++kb) {
      int kn = (kb + 1 < KB) ? kb + 1 : kb;
      short8 wf1 = *(const short8*)(wp + kn * 4096);
      short8 af1[3];
      for (int pt = 0; pt < 3; ++pt)
        af1[pt] = *(const short8*)(ap[pt] + kn * 16);

      for (int pt = 0; pt < 3; ++pt)
        acc[pt] = __builtin_amdgcn_mfma_f32_32x32x16_bf16(wf0, af0[pt],
                                                          acc[pt], 0, 0, 0);
      wf0 = wf1;
      for (int pt = 0; pt < 3; ++pt) af0[pt] = af1[pt];
    }

    if (inplace) __syncthreads();   // all K-loop reads done before overwrite

    if (!fuse_final) {
      // Epilogue: ReLU + bf16 pack; 4 b64 writes per pt-tile, already in
      // the next layer's [m][k-contiguous] layout.
      for (int pt = 0; pt < 3; ++pt) {
        int m = pt * 32 + l31;
        for (int q = 0; q < 4; ++q) {
          int n0 = wbase + 8 * q + 4 * h8;
          uint2 pk;
          pk.x = pack2bf(acc[pt][4 * q + 0], acc[pt][4 * q + 1]);
          pk.y = pack2bf(acc[pt][4 * q + 2], acc[pt][4 * q + 3]);
          *(uint2*)&bufA[m * ACT_STRIDE + n0] = pk;
        }
      }
    } else {
      // Fused final layer: per-lane relu-dot over this wave's 16 features
      // (per k-half) per pt-tile; shfl_xor(32) completes the 32-feature sum;
      // h8=0 lanes write pt 0,1 and h8=1 lanes write pt 2 (each m once).
      float w3f[16];
      for (int q = 0; q < 4; ++q) {
        float4 wv = *(const float4*)(W3 + wbase + 8 * q + 4 * h8);
        w3f[4 * q + 0] = wv.x; w3f[4 * q + 1] = wv.y;
        w3f[4 * q + 2] = wv.z; w3f[4 * q + 3] = wv.w;
      }
      float part[3];
      for (int pt = 0; pt < 3; ++pt) {
        float s = 0.f;
        for (int j = 0; j < 16; ++j) {
          float v = acc[pt][j]; v = v > 0.f ? v : 0.f;
          s += v * w3f[j];
        }
        part[pt] = s;
      }
      for (int pt = 0; pt < 3; ++pt)
        part[pt] += __shfl_xor(part[pt], 32);
      if (h8 == 0) {
        fsum[(l31)      * 9 + w] = part[0];
        fsum[(32 + l31) * 9 + w] = part[1];
      } else {
        fsum[(64 + l31) * 9 + w] = part[2];
      }
    }
  };

  float* fsum = (float*)bufE;           // bufE dead after layer 0

  short8 wf = *(const short8*)(Wp + woff);          // L0 wf preload
  __syncthreads();
  // Layer 0: bufE -> bufA (disjoint, no in-place hazard)
  run_layer(bufE, ENC_STRIDE, bufA, Wp, 4, wf, false, false, fsum);
  wf = *(const short8*)(Wp + 16384 + woff);         // L1 wf preload
  __syncthreads();
  // Layer 1: bufA -> bufA IN-PLACE (mid-layer barrier inside)
  run_layer(bufA, ACT_STRIDE, bufA, Wp + 16384, 16, wf, true, false, fsum);
  wf = *(const short8*)(Wp + 81920 + woff);         // L2 wf preload
  __syncthreads();
  // Layer 2 + final: reads bufA, writes only fsum (bufE region, disjoint)
  run_layer(bufA, ACT_STRIDE, nullptr, Wp + 81920, 16, wf, false, true, fsum);
  __syncthreads();

  // ---------------- Cross-wave reduce of fsum -> out -----------------------
  {
    int p = t >> 2;          // candidate point (0..127)
    int q = t & 3;
    float v = fsum[p * 9 + q] + fsum[p * 9 + q + 4];
    v += __shfl_xor(v, 1);
    v += __shfl_xor(v, 2);
    if (q == 0 && p < TILE_M) {
      int gi = g0 + p;
      if (gi < Ntot) out[gi] = v;
    }
  }
}

extern "C" void kernel_launch(void* const* d_in, const int* in_sizes, int n_in,
                              void* d_out, int out_size, void* d_ws,
                              size_t ws_size, hipStream_t stream) {
  const float* x     = (const float*)d_in[0];
  const float* table = (const float*)d_in[1];
  const float* W0    = (const float*)d_in[2];
  const float* W1    = (const float*)d_in[3];
  const float* W2    = (const float*)d_in[4];
  const float* W3    = (const float*)d_in[5];
  float* out = (float*)d_out;
  int N = in_sizes[0] / 2;

  unsigned short* Wp = (unsigned short*)d_ws;   // 147456 bf16 = 288 KB

  // Level params, double precision to match the Python reference exactly.
  LevelParams P;
  const double c = 1.2599210739135742;
  double m = 1.0;
  for (int l = 0; l < N_LEVELS; ++l) {
    double scale_d = 16.0 * m - 1.0;
    int res = (int)std::ceil(scale_d) + 1;
    long long sz = ((long long)res * res + 7) / 8 * 8;
    if (sz > (1LL << 19)) sz = 1LL << 19;
    P.scale[l] = (float)scale_d;
    P.res[l]   = res;
    P.size[l]  = (int)sz;
    m *= c;
  }

  int nblocks = (N + TILE_M - 1) / TILE_M;
  hipLaunchKernelGGL(pack_weights_kernel, dim3(576), dim3(256), 0, stream,
                     W0, W1, W2, Wp);
  hipLaunchKernelGGL(neural_field_kernel, dim3(nblocks), dim3(512), 0,
                     stream, x, table, Wp, W3, out, P, N);
}